// Round 1
// baseline (1030.848 us; speedup 1.0000x reference)
//
#include <hip/hip_runtime.h>
#include <cstdint>
#include <cstddef>

#define BB 4
#define SS 2048
#define HIDD 512
#define HH 8
#define DHH 64
#define DBB 8

typedef __attribute__((ext_vector_type(4))) float f32x4;
typedef __attribute__((ext_vector_type(8))) short s16x8;
typedef __attribute__((ext_vector_type(4))) short s16x4;

__device__ __forceinline__ short f2bf(float x) {
  unsigned u = __builtin_bit_cast(unsigned, x);
  u += 0x7FFFu + ((u >> 16) & 1u);
  return (short)(u >> 16);
}
__device__ __forceinline__ float bf2f(short s) {
  unsigned u = ((unsigned)(unsigned short)s) << 16;
  return __builtin_bit_cast(float, u);
}

// C[m][n] = sum_k X[m][k] * W[n][k] + bias[n]   (X: [8192,512] fp32, W: [512,512] fp32)
// MODE 0: out bf16 qh layout [B,H,S,D], value *= 0.125 (softmax scale folded)
// MODE 1: out bf16 kh layout [B,H,S,D]
// MODE 2: out bf16 vh layout [B,H,D,S] (pre-transposed for PV B-operand)
// MODE 3: out fp32 [8192,512]
template <int MODE>
__global__ __launch_bounds__(256) void gemm_xwT(const float* __restrict__ X,
                                                const float* __restrict__ W,
                                                const float* __restrict__ bias,
                                                float* __restrict__ outF,
                                                short* __restrict__ outB) {
  __shared__ short xs[64][40];   // 40-short rows: 20-bank pattern, conflict-free b128
  __shared__ short wsh[64][40];
  const int tid = threadIdx.x;
  const int wave = tid >> 6, lane = tid & 63;
  const int quad = lane >> 4, m16 = lane & 15;
  const int m0 = blockIdx.x * 64, n0 = blockIdx.y * 64;
  const int wm = (wave & 1) * 32, wn = (wave >> 1) * 32;

  f32x4 acc[2][2];
#pragma unroll
  for (int a = 0; a < 2; a++)
#pragma unroll
    for (int b2 = 0; b2 < 2; b2++) acc[a][b2] = (f32x4){0.f, 0.f, 0.f, 0.f};

  for (int k0 = 0; k0 < HIDD; k0 += 32) {
#pragma unroll
    for (int i = 0; i < 2; i++) {
      int c = tid + i * 256;
      int row = c >> 3, kc = c & 7;
      f32x4 xv = *(const f32x4*)(X + (size_t)(m0 + row) * HIDD + k0 + kc * 4);
      f32x4 wv = *(const f32x4*)(W + (size_t)(n0 + row) * HIDD + k0 + kc * 4);
      s16x4 xb, wb2;
#pragma unroll
      for (int j = 0; j < 4; j++) { xb[j] = f2bf(xv[j]); wb2[j] = f2bf(wv[j]); }
      *(s16x4*)(&xs[row][kc * 4]) = xb;
      *(s16x4*)(&wsh[row][kc * 4]) = wb2;
    }
    __syncthreads();
    s16x8 af[2], bfr[2];
    af[0] = *(const s16x8*)(&xs[wm + m16][quad * 8]);
    af[1] = *(const s16x8*)(&xs[wm + 16 + m16][quad * 8]);
    bfr[0] = *(const s16x8*)(&wsh[wn + m16][quad * 8]);
    bfr[1] = *(const s16x8*)(&wsh[wn + 16 + m16][quad * 8]);
    acc[0][0] = __builtin_amdgcn_mfma_f32_16x16x32_bf16(af[0], bfr[0], acc[0][0], 0, 0, 0);
    acc[0][1] = __builtin_amdgcn_mfma_f32_16x16x32_bf16(af[0], bfr[1], acc[0][1], 0, 0, 0);
    acc[1][0] = __builtin_amdgcn_mfma_f32_16x16x32_bf16(af[1], bfr[0], acc[1][0], 0, 0, 0);
    acc[1][1] = __builtin_amdgcn_mfma_f32_16x16x32_bf16(af[1], bfr[1], acc[1][1], 0, 0, 0);
    __syncthreads();
  }

#pragma unroll
  for (int a = 0; a < 2; a++)
#pragma unroll
    for (int b2 = 0; b2 < 2; b2++)
#pragma unroll
      for (int r = 0; r < 4; r++) {
        int m = m0 + wm + a * 16 + quad * 4 + r;   // C row = quad*4+reg (verified layout)
        int n = n0 + wn + b2 * 16 + m16;           // C col = lane&15
        float val = acc[a][b2][r] + bias[n];
        if (MODE == 0) {
          int b_ = m >> 11, s = m & 2047, h = n >> 6, d = n & 63;
          outB[((size_t)(b_ * HH + h) * SS + s) * DHH + d] = f2bf(val * 0.125f);
        } else if (MODE == 1) {
          int b_ = m >> 11, s = m & 2047, h = n >> 6, d = n & 63;
          outB[((size_t)(b_ * HH + h) * SS + s) * DHH + d] = f2bf(val);
        } else if (MODE == 2) {
          int b_ = m >> 11, s = m & 2047, h = n >> 6, d = n & 63;
          outB[((size_t)(b_ * HH + h) * DHH + d) * SS + s] = f2bf(val);
        } else {
          outF[(size_t)m * HIDD + n] = val;
        }
      }
}

// Flash attention, bias fused. One block = (b, 16 q rows, ALL 8 heads); wave w = head w.
// attn_bias is read exactly once across the whole grid.
__global__ __launch_bounds__(512) void flash_attn(const short* __restrict__ qh,
                                                  const short* __restrict__ kh,
                                                  const short* __restrict__ vh,
                                                  const float* __restrict__ attn_bias,
                                                  const float* __restrict__ Wb,
                                                  const float* __restrict__ bb,
                                                  float* __restrict__ attn_out) {
  // kv shared buffer: phase K = Kt[32 keys][520] shorts (33280B), phase V = Vt[512 d][40] (40960B)
  __shared__ short kv[20480];
  __shared__ short bp[HH][16][34];    // projected bias, bf16; 34-pad: quad rows land on distinct banks
  __shared__ short pbuf[8][16][40];   // per-wave P tile, A-layout staging; 40-short rows conflict-free
  __shared__ float wbs[72];           // Wb[8][8] + bb[8]

  const int tid = threadIdx.x;
  const int wave = tid >> 6, lane = tid & 63;
  const int quad = lane >> 4, m16 = lane & 15;
  const int b = blockIdx.x >> 7;          // 128 q-blocks per batch
  const int q0 = (blockIdx.x & 127) << 4;
  const int h = wave;

  if (tid < 72) wbs[tid] = (tid < 64) ? Wb[tid] : bb[tid - 64];

  // Q A-fragments (A[m=lane&15][k=quad*8+j]), already *0.125 from projection
  const size_t qoff = ((size_t)((b * HH + h) * SS) + q0 + m16) * DHH;
  s16x8 qf0 = *(const s16x8*)(qh + qoff + quad * 8);
  s16x8 qf1 = *(const s16x8*)(qh + qoff + 32 + quad * 8);

  f32x4 oacc[4];
#pragma unroll
  for (int dt = 0; dt < 4; dt++) oacc[dt] = (f32x4){0.f, 0.f, 0.f, 0.f};
  float m_r[4], l_r[4];
#pragma unroll
  for (int r = 0; r < 4; r++) { m_r[r] = -3.0e38f; l_r[r] = 0.f; }

  __syncthreads();  // wbs ready

  for (int k0 = 0; k0 < SS; k0 += 32) {
    // ---- Phase A: stage K tile (all heads) + project bias tile ----
#pragma unroll
    for (int i = 0; i < 4; i++) {
      int c = tid + i * 512;
      int key = c >> 6, rest = c & 63;
      int hh2 = rest >> 3, dc = rest & 7;
      s16x8 val = *(const s16x8*)(kh + ((size_t)((b * HH + hh2) * SS) + k0 + key) * DHH + dc * 8);
      *(s16x8*)(&kv[key * 520 + hh2 * 64 + dc * 8]) = val;
    }
    {
      int ql = tid >> 5, kl = tid & 31;  // 512 threads = 16x32 (q,k) pairs
      const float* bptr = attn_bias + ((size_t)(b * SS + q0 + ql) * SS + k0 + kl) * DBB;
      f32x4 b0 = *(const f32x4*)(bptr);
      f32x4 b1 = *(const f32x4*)(bptr + 4);
#pragma unroll
      for (int h2 = 0; h2 < 8; h2++) {
        float a2 = wbs[64 + h2];
#pragma unroll
        for (int d = 0; d < 4; d++) {
          a2 += b0[d] * wbs[h2 * 8 + d];
          a2 += b1[d] * wbs[h2 * 8 + 4 + d];
        }
        bp[h2][ql][kl] = f2bf(a2);
      }
    }
    __syncthreads();  // B1: K + bias ready

    // ---- QK^T: 16q x 32k scores for this wave's head ----
    f32x4 sc[2];
#pragma unroll
    for (int nt = 0; nt < 2; nt++) {
      s16x8 kf0 = *(const s16x8*)(&kv[(nt * 16 + m16) * 520 + h * 64 + quad * 8]);
      s16x8 kf1 = *(const s16x8*)(&kv[(nt * 16 + m16) * 520 + h * 64 + 32 + quad * 8]);
      f32x4 z = (f32x4){0.f, 0.f, 0.f, 0.f};
      z = __builtin_amdgcn_mfma_f32_16x16x32_bf16(qf0, kf0, z, 0, 0, 0);
      z = __builtin_amdgcn_mfma_f32_16x16x32_bf16(qf1, kf1, z, 0, 0, 0);
      sc[nt] = z;
    }

    // ---- online softmax (C layout: row = quad*4+r, col = m16) ----
#pragma unroll
    for (int r = 0; r < 4; r++) {
      int row = quad * 4 + r;
      float s0 = sc[0][r] + bf2f(bp[h][row][m16]);
      float s1 = sc[1][r] + bf2f(bp[h][row][16 + m16]);
      float v = fmaxf(s0, s1);
      v = fmaxf(v, __shfl_xor(v, 1, 16));
      v = fmaxf(v, __shfl_xor(v, 2, 16));
      v = fmaxf(v, __shfl_xor(v, 4, 16));
      v = fmaxf(v, __shfl_xor(v, 8, 16));
      float nm = fmaxf(m_r[r], v);
      float al = __expf(m_r[r] - nm);
      m_r[r] = nm;
      float p0 = __expf(s0 - nm);
      float p1 = __expf(s1 - nm);
      float rs = p0 + p1;
      rs += __shfl_xor(rs, 1, 16);
      rs += __shfl_xor(rs, 2, 16);
      rs += __shfl_xor(rs, 4, 16);
      rs += __shfl_xor(rs, 8, 16);
      l_r[r] = l_r[r] * al + rs;
#pragma unroll
      for (int dt = 0; dt < 4; dt++) oacc[dt][r] *= al;
      pbuf[wave][row][m16] = f2bf(p0);
      pbuf[wave][row][16 + m16] = f2bf(p1);
    }
    __syncthreads();  // B2: all waves done reading K from kv

    // ---- stage V tile transposed Vt[d][key] (vh is [B,H,D,S]) ----
#pragma unroll
    for (int i = 0; i < 4; i++) {
      int c = tid + i * 512;
      int d = c >> 2, kc = c & 3;
      s16x8 val = *(const s16x8*)(vh + ((size_t)((b * HH + (d >> 6)) * DHH + (d & 63)) * SS) + k0 + kc * 8);
      *(s16x8*)(&kv[d * 40 + kc * 8]) = val;
    }
    __syncthreads();  // B3: V ready

    // ---- PV: O += P(16x32) @ V(32x64) ----
    s16x8 pf = *(const s16x8*)(&pbuf[wave][m16][quad * 8]);
#pragma unroll
    for (int dt = 0; dt < 4; dt++) {
      s16x8 vf = *(const s16x8*)(&kv[(h * 64 + dt * 16 + m16) * 40 + quad * 8]);
      oacc[dt] = __builtin_amdgcn_mfma_f32_16x16x32_bf16(pf, vf, oacc[dt], 0, 0, 0);
    }
    __syncthreads();  // B4: all waves done reading V before next K staging
  }

  // epilogue: attn_out[b, s, h*64+d] fp32
#pragma unroll
  for (int dt = 0; dt < 4; dt++)
#pragma unroll
    for (int r = 0; r < 4; r++) {
      float val = oacc[dt][r] / l_r[r];
      attn_out[(size_t)(b * SS + q0 + quad * 4 + r) * HIDD + h * 64 + dt * 16 + m16] = val;
    }
}

extern "C" void kernel_launch(void* const* d_in, const int* in_sizes, int n_in,
                              void* d_out, int out_size, void* d_ws, size_t ws_size,
                              hipStream_t stream) {
  const float* q = (const float*)d_in[0];
  const float* k = (const float*)d_in[1];
  const float* v = (const float*)d_in[2];
  const float* attn_bias = (const float*)d_in[3];
  const float* Wq = (const float*)d_in[4];
  const float* bq = (const float*)d_in[5];
  const float* Wk = (const float*)d_in[6];
  const float* bk = (const float*)d_in[7];
  const float* Wv = (const float*)d_in[8];
  const float* bv = (const float*)d_in[9];
  const float* Wb = (const float*)d_in[10];
  const float* bb = (const float*)d_in[11];
  const float* Wo = (const float*)d_in[12];
  const float* bo = (const float*)d_in[13];
  float* out = (float*)d_out;

  // workspace: qh/kh/vh bf16 (8.39 MB each) + attn fp32 (16.8 MB) = 41.9 MB
  short* qh = (short*)d_ws;
  short* kh = qh + (size_t)4194304;
  short* vh = kh + (size_t)4194304;
  float* attn_ws = (float*)(vh + (size_t)4194304);

  dim3 g(128, 8), blk(256);
  gemm_xwT<0><<<g, blk, 0, stream>>>(q, Wq, bq, nullptr, qh);
  gemm_xwT<1><<<g, blk, 0, stream>>>(k, Wk, bk, nullptr, kh);
  gemm_xwT<2><<<g, blk, 0, stream>>>(v, Wv, bv, nullptr, vh);
  flash_attn<<<512, 512, 0, stream>>>(qh, kh, vh, attn_bias, Wb, bb, attn_ws);
  gemm_xwT<3><<<g, blk, 0, stream>>>(attn_ws, Wo, bo, out, nullptr);
}